// Round 2
// baseline (224.609 us; speedup 1.0000x reference)
//
#include <hip/hip_runtime.h>

#define NB 256
#define NC 256
#define NL 25
#define ND 257
#define NHID 64
#define NOUT 32

__device__ __forceinline__ float lrelu(float x) {
    return fmaxf(x, 0.0f) + 0.01f * fminf(x, 0.0f);
}

// Transpose g0_w (64 x 514) into wt[c][j], c in [0,257), j in [0,128):
//   j <  64 : A-part = g0_w[j][c]        (applies to feats[m], the x_i half)
//   j >= 64 : B-part = g0_w[j-64][257+c] (applies to feats[l], the x_j half)
__global__ void k_transpose(const float* __restrict__ g0, float* __restrict__ wt) {
    __shared__ float tile[64][65];
    const int cbase = blockIdx.x * 64;
    const int jh = blockIdx.y;  // 0 = A half, 1 = B half
    const int tid = threadIdx.x;
    for (int i = tid; i < 64 * 64; i += 256) {
        int r = i >> 6;        // source row k
        int cc = i & 63;       // col within tile
        int c = cbase + cc;
        float v = 0.0f;
        if (c < ND) v = g0[r * (2 * ND) + jh * ND + c];
        tile[r][cc] = v;
    }
    __syncthreads();
    for (int i = tid; i < 64 * 64; i += 256) {
        int cc = i >> 6;
        int r = i & 63;
        int c = cbase + cc;
        if (c < ND) wt[c * 128 + jh * 64 + r] = tile[r][cc];
    }
}

__global__ __launch_bounds__(256, 1)
void k_main(const float* __restrict__ x_img,
            const float* __restrict__ wt,      // [257][128] fp32
            const float* __restrict__ g0_b,
            const float* __restrict__ g1_w,
            const float* __restrict__ g1_b,
            const float* __restrict__ post_w,
            const float* __restrict__ post_b,
            const float* __restrict__ out_w,
            const float* __restrict__ out_b,
            float* __restrict__ out)
{
    __shared__ __align__(16) float xs[NC * NL];   // x_img slice, native [c][p] layout
    __shared__ __align__(16) float u_s[NL * 64];  // u[p][k], k XOR-swizzled by ((p&7)<<2)
    __shared__ __align__(16) float v_s[NL * 64];  // v[p][k], same swizzle
    __shared__ __align__(16) float b0_s[64];
    __shared__ float s_wave[4 * 64];
    __shared__ float sfin[64];
    __shared__ float z_s[64];

    const int tid = threadIdx.x;
    const int b = blockIdx.x;
    const int lane = tid & 63;
    const int wid = tid >> 6;

    // ---- stage x_img slice (coalesced float4; 6400 floats) ----
    {
        const float4* src = (const float4*)(x_img + (size_t)b * (NC * NL));
        float4* dst = (float4*)xs;
        for (int i = tid; i < (NC * NL) / 4; i += 256) dst[i] = src[i];
    }
    if (tid < 64) b0_s[tid] = g0_b[tid];
    __syncthreads();

    // ---- phase 1: u[p][k] = sum_c A[k][c]*f[p][c] ; v[p][k] = sum_c B[k][c]*f[p][c]
    // task decode: 160 tasks = (k4 in 16) x (uv in 2) x (p5 in 5), 5 p's per task
    if (tid < 160) {
        const int k4 = tid & 15;
        const int uv = (tid >> 4) & 1;
        const int p5 = tid >> 5;  // 0..4
        float4 acc[5];
        #pragma unroll
        for (int q = 0; q < 5; ++q) acc[q] = make_float4(0.f, 0.f, 0.f, 0.f);
        const float4* wp = (const float4*)(wt + uv * 64 + k4 * 4);  // row stride 32 float4
        #pragma unroll 4
        for (int c = 0; c < 256; ++c) {
            float4 w4 = wp[c * 32];
            #pragma unroll
            for (int q = 0; q < 5; ++q) {
                float f = xs[c * NL + p5 * 5 + q];  // LDS broadcast
                acc[q].x += w4.x * f; acc[q].y += w4.y * f;
                acc[q].z += w4.z * f; acc[q].w += w4.w * f;
            }
        }
        {   // c = 256: coordinate feature, f[p][256] = (float)p
            float4 w4 = wp[256 * 32];
            #pragma unroll
            for (int q = 0; q < 5; ++q) {
                float f = (float)(p5 * 5 + q);
                acc[q].x += w4.x * f; acc[q].y += w4.y * f;
                acc[q].z += w4.z * f; acc[q].w += w4.w * f;
            }
        }
        float* dstbuf = uv ? v_s : u_s;
        #pragma unroll
        for (int q = 0; q < 5; ++q) {
            int p = p5 * 5 + q;
            int w = p * 64 + ((k4 * 4) ^ ((p & 7) << 2));
            *(float4*)&dstbuf[w] = acc[q];
        }
    }
    __syncthreads();

    // ---- phase 2: S[j] = sum over 625 pairs of lrelu(g1[j,:] . h0(pair) + b1[j])
    // 3 pair-slots per thread (3*256 = 768 >= 625)
    int mm[3], ll[3];
    bool valid[3];
    #pragma unroll
    for (int s = 0; s < 3; ++s) {
        int pp = s * 256 + tid;
        valid[s] = (pp < NL * NL);
        if (pp > NL * NL - 1) pp = NL * NL - 1;
        int l = pp / NL;
        int m = pp - l * NL;
        mm[s] = m; ll[s] = l;
    }

    // h0[s][k] = lrelu(u[m][k] + v[l][k] + b0[k])  (held in registers: 3*16 float4)
    float4 h0[3][16];
    #pragma unroll
    for (int s = 0; s < 3; ++s) {
        const int m = mm[s], l = ll[s];
        #pragma unroll
        for (int k4 = 0; k4 < 16; ++k4) {
            float4 u4 = *(const float4*)&u_s[m * 64 + ((k4 * 4) ^ ((m & 7) << 2))];
            float4 v4 = *(const float4*)&v_s[l * 64 + ((k4 * 4) ^ ((l & 7) << 2))];
            float4 b4 = *(const float4*)&b0_s[k4 * 4];
            float4 h;
            h.x = lrelu(u4.x + v4.x + b4.x);
            h.y = lrelu(u4.y + v4.y + b4.y);
            h.z = lrelu(u4.z + v4.z + b4.z);
            h.w = lrelu(u4.w + v4.w + b4.w);
            h0[s][k4] = h;
        }
    }

    float s_reg = 0.0f;  // lane owns j == lane
    #pragma unroll 1
    for (int j4 = 0; j4 < 16; ++j4) {
        float tot[4];
        #pragma unroll
        for (int jj = 0; jj < 4; ++jj) {
            const int j = j4 * 4 + jj;
            const float4* grow = (const float4*)(g1_w + j * 64);  // wave-uniform -> s_load
            float4 a0 = make_float4(0.f,0.f,0.f,0.f);
            float4 a1 = make_float4(0.f,0.f,0.f,0.f);
            float4 a2 = make_float4(0.f,0.f,0.f,0.f);
            #pragma unroll
            for (int k4 = 0; k4 < 16; ++k4) {
                float4 g = grow[k4];
                a0.x += g.x * h0[0][k4].x; a0.y += g.y * h0[0][k4].y;
                a0.z += g.z * h0[0][k4].z; a0.w += g.w * h0[0][k4].w;
                a1.x += g.x * h0[1][k4].x; a1.y += g.y * h0[1][k4].y;
                a1.z += g.z * h0[1][k4].z; a1.w += g.w * h0[1][k4].w;
                a2.x += g.x * h0[2][k4].x; a2.y += g.y * h0[2][k4].y;
                a2.z += g.z * h0[2][k4].z; a2.w += g.w * h0[2][k4].w;
            }
            const float bj = g1_b[j];
            float d0 = (a0.x + a0.y) + (a0.z + a0.w);
            float d1 = (a1.x + a1.y) + (a1.z + a1.w);
            float d2 = (a2.x + a2.y) + (a2.z + a2.w);
            float t0 = valid[0] ? lrelu(d0 + bj) : 0.0f;
            float t1 = valid[1] ? lrelu(d1 + bj) : 0.0f;
            float t2 = valid[2] ? lrelu(d2 + bj) : 0.0f;
            tot[jj] = t0 + t1 + t2;
        }
        // 4 interleaved 64-lane xor butterflies (latency overlapped)
        #pragma unroll
        for (int jj = 0; jj < 4; ++jj) tot[jj] += __shfl_xor(tot[jj], 1, 64);
        #pragma unroll
        for (int jj = 0; jj < 4; ++jj) tot[jj] += __shfl_xor(tot[jj], 2, 64);
        #pragma unroll
        for (int jj = 0; jj < 4; ++jj) tot[jj] += __shfl_xor(tot[jj], 4, 64);
        #pragma unroll
        for (int jj = 0; jj < 4; ++jj) tot[jj] += __shfl_xor(tot[jj], 8, 64);
        #pragma unroll
        for (int jj = 0; jj < 4; ++jj) tot[jj] += __shfl_xor(tot[jj], 16, 64);
        #pragma unroll
        for (int jj = 0; jj < 4; ++jj) tot[jj] += __shfl_xor(tot[jj], 32, 64);
        #pragma unroll
        for (int jj = 0; jj < 4; ++jj)
            s_reg += (lane == j4 * 4 + jj) ? tot[jj] : 0.0f;
    }
    s_wave[wid * 64 + lane] = s_reg;
    __syncthreads();

    // ---- final MLP (wave 0 only) ----
    if (tid < 64) {
        float s = s_wave[tid] + s_wave[64 + tid] + s_wave[128 + tid] + s_wave[192 + tid];
        sfin[tid] = s;
        // z = lrelu(post_w @ s + post_b)
        float acc = post_b[tid];
        #pragma unroll 8
        for (int k = 0; k < 64; ++k) acc += post_w[tid * 64 + k] * sfin[k];
        z_s[tid] = lrelu(acc);
        if (tid < 32) {
            float acc2 = out_b[tid];
            #pragma unroll 8
            for (int k = 0; k < 64; ++k) acc2 += out_w[tid * 64 + k] * z_s[k];
            out[b * NOUT + tid] = lrelu(acc2);
        }
    }
}

extern "C" void kernel_launch(void* const* d_in, const int* in_sizes, int n_in,
                              void* d_out, int out_size, void* d_ws, size_t ws_size,
                              hipStream_t stream) {
    const float* x_img  = (const float*)d_in[0];
    const float* g0_w   = (const float*)d_in[1];
    const float* g0_b   = (const float*)d_in[2];
    const float* g1_w   = (const float*)d_in[3];
    const float* g1_b   = (const float*)d_in[4];
    const float* post_w = (const float*)d_in[5];
    const float* post_b = (const float*)d_in[6];
    const float* out_w  = (const float*)d_in[7];
    const float* out_b  = (const float*)d_in[8];
    float* out = (float*)d_out;
    float* wt  = (float*)d_ws;  // 257*128 fp32 = 131.6 KB

    k_transpose<<<dim3(5, 2), 256, 0, stream>>>(g0_w, wt);
    k_main<<<dim3(NB), 256, 0, stream>>>(x_img, wt, g0_b, g1_w, g1_b,
                                         post_w, post_b, out_w, out_b, out);
}

// Round 5
// 167.434 us; speedup vs baseline: 1.3415x; 1.3415x over previous
//
#include <hip/hip_runtime.h>

#define NB 256
#define NC 256
#define NL 25
#define ND 257
#define NHID 64
#define NOUT 32

// dynamic LDS layout (float offsets)
#define OFF_H0   0        // 24576 floats: h0 chunk, 6 batches x 64 pairs x 64 k (96 KB)
                          //   aliases: xs (6400 floats, phase 1) ; red (64x264, final reduce)
#define OFF_P    24576    // 6400 floats: P[chalf][uv][25][64]
#define OFF_B0   30976    // 64
#define OFF_SF   31040    // 64
#define OFF_Z    31104    // 64
#define SMEM_FLOATS 31168 // 124,672 bytes

__device__ __forceinline__ float lrelu(float x) {
    return fmaxf(x, 0.0f) + 0.01f * fminf(x, 0.0f);
}

// Transpose g0_w (64 x 514) into wt[c][j], c in [0,257), j in [0,128):
//   j <  64 : A-part = g0_w[j][c]        (applies to feats[m], the x_i half)
//   j >= 64 : B-part = g0_w[j-64][257+c] (applies to feats[l], the x_j half)
__global__ void k_transpose(const float* __restrict__ g0, float* __restrict__ wt) {
    __shared__ float tile[64][65];
    const int cbase = blockIdx.x * 64;
    const int jh = blockIdx.y;
    const int tid = threadIdx.x;
    for (int i = tid; i < 64 * 64; i += 256) {
        int r = i >> 6;
        int cc = i & 63;
        int c = cbase + cc;
        float v = 0.0f;
        if (c < ND) v = g0[r * (2 * ND) + jh * ND + c];
        tile[r][cc] = v;
    }
    __syncthreads();
    for (int i = tid; i < 64 * 64; i += 256) {
        int cc = i >> 6;
        int r = i & 63;
        int c = cbase + cc;
        if (c < ND) wt[c * 128 + jh * 64 + r] = tile[r][cc];
    }
}

__global__ __launch_bounds__(512, 2)
void k_main(const float* __restrict__ x_img,
            const float* __restrict__ wt,      // [257][128]
            const float* __restrict__ g0_b,
            const float* __restrict__ g1_w,
            const float* __restrict__ g1_b,
            const float* __restrict__ post_w,
            const float* __restrict__ post_b,
            const float* __restrict__ out_w,
            const float* __restrict__ out_b,
            float* __restrict__ out)
{
    extern __shared__ float smem[];
    float* h0c = smem + OFF_H0;
    float* xs  = smem + OFF_H0;   // alias, live only in phase 1
    float* red = smem + OFF_H0;   // alias, live only after phase 2
    float* Pb  = smem + OFF_P;
    float* b0s = smem + OFF_B0;
    float* sf  = smem + OFF_SF;
    float* zs  = smem + OFF_Z;

    const int tid  = threadIdx.x;
    const int b    = blockIdx.x;
    const int lane = tid & 63;
    const int wid  = tid >> 6;

    // ---- stage x slice: 6400 floats, coalesced float4 ----
    {
        const float4* src = (const float4*)(x_img + (size_t)b * (NC * NL));
        float4* dst = (float4*)xs;
        for (int i = tid; i < 1600; i += 512) dst[i] = src[i];
    }
    if (tid < 64) b0s[tid] = g0_b[tid];
    __syncthreads();

    // ---- phase 1: P[chalf][uv][p][k] partial projections ----
    // 512 threads = chalf(2) x pgrp(8: p-groups 3,3,3,3,3,3,3,4) x uv(2) x k4(16)
    {
        const int r     = tid & 255;
        const int chalf = tid >> 8;
        const int k4    = r & 15;
        const int uv    = (r >> 4) & 1;
        const int pgrp  = r >> 5;
        const int pstart = pgrp * 3;
        const bool p4   = (pgrp == 7);
        float4 a0 = {0.f,0.f,0.f,0.f}, a1 = a0, a2 = a0, a3 = a0;
        const float4* wp = ((const float4*)wt) + (uv * 16 + k4);  // row stride 32 float4
        const float* xrow = xs + pstart;
        const int c0   = chalf ? 128 : 0;
        const int cend = chalf ? 256 : 128;
        #pragma unroll 2
        for (int c = c0; c < cend; ++c) {
            const float4 w4 = wp[c * 32];
            const float f0 = xrow[c * 25 + 0];
            const float f1 = xrow[c * 25 + 1];
            const float f2 = xrow[c * 25 + 2];
            a0.x = fmaf(w4.x, f0, a0.x); a0.y = fmaf(w4.y, f0, a0.y);
            a0.z = fmaf(w4.z, f0, a0.z); a0.w = fmaf(w4.w, f0, a0.w);
            a1.x = fmaf(w4.x, f1, a1.x); a1.y = fmaf(w4.y, f1, a1.y);
            a1.z = fmaf(w4.z, f1, a1.z); a1.w = fmaf(w4.w, f1, a1.w);
            a2.x = fmaf(w4.x, f2, a2.x); a2.y = fmaf(w4.y, f2, a2.y);
            a2.z = fmaf(w4.z, f2, a2.z); a2.w = fmaf(w4.w, f2, a2.w);
            if (p4) {
                const float f3 = xrow[c * 25 + 3];
                a3.x = fmaf(w4.x, f3, a3.x); a3.y = fmaf(w4.y, f3, a3.y);
                a3.z = fmaf(w4.z, f3, a3.z); a3.w = fmaf(w4.w, f3, a3.w);
            }
        }
        if (chalf) {  // c = 256: coordinate feature f[p][256] = (float)p
            const float4 w4 = wp[256 * 32];
            const float f0 = (float)(pstart + 0);
            const float f1 = (float)(pstart + 1);
            const float f2 = (float)(pstart + 2);
            a0.x = fmaf(w4.x, f0, a0.x); a0.y = fmaf(w4.y, f0, a0.y);
            a0.z = fmaf(w4.z, f0, a0.z); a0.w = fmaf(w4.w, f0, a0.w);
            a1.x = fmaf(w4.x, f1, a1.x); a1.y = fmaf(w4.y, f1, a1.y);
            a1.z = fmaf(w4.z, f1, a1.z); a1.w = fmaf(w4.w, f1, a1.w);
            a2.x = fmaf(w4.x, f2, a2.x); a2.y = fmaf(w4.y, f2, a2.y);
            a2.z = fmaf(w4.z, f2, a2.z); a2.w = fmaf(w4.w, f2, a2.w);
            if (p4) {
                const float f3 = (float)(pstart + 3);
                a3.x = fmaf(w4.x, f3, a3.x); a3.y = fmaf(w4.y, f3, a3.y);
                a3.z = fmaf(w4.z, f3, a3.z); a3.w = fmaf(w4.w, f3, a3.w);
            }
        }
        float* dst = Pb + (chalf * 2 + uv) * 1600;
        *(float4*)&dst[(pstart + 0) * 64 + k4 * 4] = a0;
        *(float4*)&dst[(pstart + 1) * 64 + k4 * 4] = a1;
        *(float4*)&dst[(pstart + 2) * 64 + k4 * 4] = a2;
        if (p4) *(float4*)&dst[(pstart + 3) * 64 + k4 * 4] = a3;
    }
    __syncthreads();  // P ready; xs dead

    // ---- phase 2: S[j] = sum_pairs lrelu(g1[j] . h0(pair) + b1[j]) ----
    // 20 tasks = batch(10, 64 pairs each) x jhalf(2). Wave w owns T = w, w+8, w+16.
    // All of a wave's tasks share jhalf = w&1 -> acc[32] persists across tasks.
    // Chunks: ch0 = batches 0..5 (tasks 0..11), ch1 = batches 6..9 (tasks 12..19):
    // per-SIMD load = 3 + 2 task-units, exactly balanced.
    float acc[32];
    #pragma unroll
    for (int j = 0; j < 32; ++j) acc[j] = 0.f;
    const int jbase = __builtin_amdgcn_readfirstlane((wid & 1) * 32);

    #pragma unroll 1
    for (int ch = 0; ch < 2; ++ch) {
        const int cbase = ch ? 384 : 0;   // first pair of chunk
        const int slots = ch ? 256 : 384; // pair slots in chunk
        __syncthreads();                  // prev chunk consumed
        // -- 2a: fill h0c (k4-swizzled rows) --
        const float4* P4 = (const float4*)Pb;
        const int rounds = (slots * 16) >> 9;  // 12 or 8
        #pragma unroll 1
        for (int rr = 0; rr < rounds; ++rr) {
            const int idx = rr * 512 + tid;
            const int k4 = idx & 15;
            const int lp = idx >> 4;
            int pp = cbase + lp; pp = (pp > 624) ? 624 : pp;
            const int l = (pp * 5243) >> 17;   // pp / 25
            const int m = pp - l * 25;
            const float4 u0 = P4[         m * 16 + k4];
            const float4 v0 = P4[ 400 +   l * 16 + k4];
            const float4 u1 = P4[ 800 +   m * 16 + k4];
            const float4 v1 = P4[1200 +   l * 16 + k4];
            const float4 b4 = *(const float4*)&b0s[k4 * 4];
            float4 h;
            h.x = lrelu(u0.x + u1.x + v0.x + v1.x + b4.x);
            h.y = lrelu(u0.y + u1.y + v0.y + v1.y + b4.y);
            h.z = lrelu(u0.z + u1.z + v0.z + v1.z + b4.z);
            h.w = lrelu(u0.w + u1.w + v0.w + v1.w + b4.w);
            *(float4*)&h0c[lp * 64 + ((k4 ^ (lp & 15)) << 2)] = h;
        }
        __syncthreads();
        // -- 2b: per-wave tasks --
        #pragma unroll 1
        for (int T = wid; T < 20; T += 8) {
            const int batch = T >> 1;
            if (ch ? (batch < 6) : (batch >= 6)) continue;
            const int pp = batch * 64 + lane;
            const bool ok = pp < 625;
            const int lp = ((pp > 624) ? 624 : pp) - cbase;
            float4 h[16];
            const int hb = lp * 64;
            const int sw = lp & 15;
            #pragma unroll
            for (int k = 0; k < 16; ++k)
                h[k] = *(const float4*)&h0c[hb + ((k ^ sw) << 2)];
            #pragma unroll
            for (int j = 0; j < 32; ++j) {
                const float4* __restrict__ gr =
                    (const float4*)(g1_w + (size_t)(jbase + j) * 64);  // wave-uniform -> s_load
                float4 q0 = {0.f,0.f,0.f,0.f}, q1 = q0, q2 = q0, q3 = q0;
                #pragma unroll
                for (int k = 0; k < 4; ++k) {
                    float4 g;
                    g = gr[k*4+0];
                    q0.x = fmaf(g.x, h[k*4+0].x, q0.x); q0.y = fmaf(g.y, h[k*4+0].y, q0.y);
                    q0.z = fmaf(g.z, h[k*4+0].z, q0.z); q0.w = fmaf(g.w, h[k*4+0].w, q0.w);
                    g = gr[k*4+1];
                    q1.x = fmaf(g.x, h[k*4+1].x, q1.x); q1.y = fmaf(g.y, h[k*4+1].y, q1.y);
                    q1.z = fmaf(g.z, h[k*4+1].z, q1.z); q1.w = fmaf(g.w, h[k*4+1].w, q1.w);
                    g = gr[k*4+2];
                    q2.x = fmaf(g.x, h[k*4+2].x, q2.x); q2.y = fmaf(g.y, h[k*4+2].y, q2.y);
                    q2.z = fmaf(g.z, h[k*4+2].z, q2.z); q2.w = fmaf(g.w, h[k*4+2].w, q2.w);
                    g = gr[k*4+3];
                    q3.x = fmaf(g.x, h[k*4+3].x, q3.x); q3.y = fmaf(g.y, h[k*4+3].y, q3.y);
                    q3.z = fmaf(g.z, h[k*4+3].z, q3.z); q3.w = fmaf(g.w, h[k*4+3].w, q3.w);
                }
                const float s0 = (q0.x + q0.y) + (q0.z + q0.w);
                const float s1 = (q1.x + q1.y) + (q1.z + q1.w);
                const float s2 = (q2.x + q2.y) + (q2.z + q2.w);
                const float s3 = (q3.x + q3.y) + (q3.z + q3.w);
                const float d  = (s0 + s1) + (s2 + s3);
                const float t  = lrelu(d + g1_b[jbase + j]);
                acc[j] += ok ? t : 0.0f;
            }
        }
    }

    // ---- reduce acc across lanes & waves ----
    __syncthreads();  // h0c dead -> red usable
    {
        const int col = ((wid >> 1) << 6) + lane;  // 0..255 per jhalf group
        #pragma unroll
        for (int j = 0; j < 32; ++j)
            red[(jbase + j) * 264 + col] = acc[j];
    }
    __syncthreads();
    {
        const int j = tid >> 3, seg = tid & 7;
        const float* rp = red + j * 264 + seg;
        float s = 0.f;
        #pragma unroll
        for (int i = 0; i < 32; ++i) s += rp[i * 8];
        s += __shfl_xor(s, 1, 64);
        s += __shfl_xor(s, 2, 64);
        s += __shfl_xor(s, 4, 64);
        if (seg == 0) sf[j] = s;
    }
    __syncthreads();

    // ---- final MLP (wave 0) ----
    if (tid < 64) {
        float a = post_b[tid];
        #pragma unroll 8
        for (int k = 0; k < 64; ++k) a = fmaf(post_w[tid * 64 + k], sf[k], a);
        zs[tid] = lrelu(a);
        if (tid < 32) {
            float a2 = out_b[tid];
            #pragma unroll 8
            for (int k = 0; k < 64; ++k) a2 = fmaf(out_w[tid * 64 + k], zs[k], a2);
            out[b * NOUT + tid] = lrelu(a2);
        }
    }
}

extern "C" void kernel_launch(void* const* d_in, const int* in_sizes, int n_in,
                              void* d_out, int out_size, void* d_ws, size_t ws_size,
                              hipStream_t stream) {
    const float* x_img  = (const float*)d_in[0];
    const float* g0_w   = (const float*)d_in[1];
    const float* g0_b   = (const float*)d_in[2];
    const float* g1_w   = (const float*)d_in[3];
    const float* g1_b   = (const float*)d_in[4];
    const float* post_w = (const float*)d_in[5];
    const float* post_b = (const float*)d_in[6];
    const float* out_w  = (const float*)d_in[7];
    const float* out_b  = (const float*)d_in[8];
    float* out = (float*)d_out;
    float* wt  = (float*)d_ws;  // 257*128 fp32

    // dynamic LDS 124.7 KB > 64 KB: opt in every call (idempotent, capture-safe)
    hipFuncSetAttribute((const void*)k_main,
                        hipFuncAttributeMaxDynamicSharedMemorySize,
                        SMEM_FLOATS * 4);

    k_transpose<<<dim3(5, 2), 256, 0, stream>>>(g0_w, wt);
    k_main<<<dim3(NB), 512, SMEM_FLOATS * 4, stream>>>(x_img, wt, g0_b, g1_w, g1_b,
                                                       post_w, post_b, out_w, out_b, out);
}